// Round 10
// baseline (149.499 us; speedup 1.0000x reference)
//
#include <hip/hip_runtime.h>
#include <hip/hip_bf16.h>
#include <math.h>

#define N_ROWS 32768
#define H      512
#define GV     640
#define V      320
#define DG     128
#define BM     32           // rows per block
#define NT     16           // K-steps of 32 (H=512)

typedef __attribute__((ext_vector_type(4))) float f32x4;
typedef __attribute__((ext_vector_type(8))) short short8v;   // 8 bf16

static __device__ __forceinline__ short f2bf(float f) {      // fp32 -> bf16 RNE
    unsigned int u = __float_as_uint(f);
    u += 0x7fffu + ((u >> 16) & 1u);
    return (short)(u >> 16);
}

// Pack W (fp32 [512][640]) into bf16 B-fragments for mfma_f32_16x16x32_bf16:
// frag (t, ct): lane l supplies B[k = t*32 + 8*(l>>4) + i][col = ct*16 + (l&15)], i=0..7.
// wp[(((t*40 + ct)*64 + l)*8 + i)] -> main-kernel B-load = 1 coalesced ushort8.
__global__ __launch_bounds__(256)
void pack_w(const float* __restrict__ W, short* __restrict__ wp)
{
    int gid = blockIdx.x * 256 + threadIdx.x;   // 40960 = 16 t * 40 ct * 64 l
    int l   = gid & 63;
    int ct  = (gid >> 6) % 40;
    int t   = gid / (40 * 64);
    int row = t * 32 + 8 * (l >> 4);
    int col = ct * 16 + (l & 15);
    short8v pk;
    #pragma unroll
    for (int i = 0; i < 8; ++i)
        pk[i] = f2bf(W[(size_t)(row + i) * GV + col]);
    *(short8v*)(wp + (size_t)gid * 8) = pk;
}

// Pack hidden (fp32 [32768][512]) into bf16 A-fragments, stored in the OUT buffer.
// frag (rt, t): lane l supplies A[row = rt*16 + (l&15)][k = t*32 + 8*(l>>4) + i], i=0..7.
__global__ __launch_bounds__(256)
void pack_a(const float* __restrict__ hidden, short* __restrict__ ap)
{
    int gid = blockIdx.x * 256 + threadIdx.x;   // 2,097,152 = 2048 rt * 16 t * 64 l
    int l   = gid & 63;
    int t   = (gid >> 6) & 15;
    int rt  = gid >> 10;
    const float* src = hidden + (size_t)(rt * 16 + (l & 15)) * H + t * 32 + 8 * (l >> 4);
    float4 x0 = *(const float4*)src;
    float4 x1 = *(const float4*)(src + 4);
    short8v pk;
    pk[0] = f2bf(x0.x); pk[1] = f2bf(x0.y); pk[2] = f2bf(x0.z); pk[3] = f2bf(x0.w);
    pk[4] = f2bf(x1.x); pk[5] = f2bf(x1.y); pk[6] = f2bf(x1.z); pk[7] = f2bf(x1.w);
    *(short8v*)(ap + (size_t)gid * 8) = pk;
}

// Fused: bf16-MFMA logits GEMM + gumbel argmax + softmax marginal + codevector gather.
// 512 threads = 8 waves, wave grid 2(M) x 4(N): wave (wm,wn) owns row-tile blockIdx*2+wm
// (16 rows) x cols wn*160..+159. Each wave's 160 cols lie entirely in ONE softmax group
// (wn<2 -> group0, else group1); group partner wave = wid^1.
// Epilogue reduces IN the C-fragment layout: lane (q=tn>>4, cn=tn&15) holds rows 4q+r;
// per-row reduction = 10-chain local + 4-step 16-lane butterfly (all 16 rows in parallel),
// then a tiny LDS exchange with the partner wave. Gumbel is prefetched in fragment layout
// BEFORE the K-loop so its latency hides under the MFMAs. 3 barriers, ~8KB LDS.
__global__ __launch_bounds__(512, 4)
void gumbel_vq_main(const short* apack,               // aliases out! (no restrict)
                    const int*   __restrict__ mask,
                    const float* __restrict__ gumbel,
                    const short* __restrict__ wpack,
                    const float* __restrict__ bias,
                    const float* __restrict__ codevec,
                    float* out,                       // aliases apack (no restrict)
                    float* __restrict__ ws)
{
    __shared__ float4 ex[8][16];          // per-wave per-row (zmax, zidx, lmax, -)
    __shared__ float  ex2[8][16];         // per-wave per-row psum
    __shared__ float  mg[2 * GV];         // per-wm marginal partials
    __shared__ int    rowtab[BM][2];      // winning codevector idx per row per group

    const int tid = threadIdx.x;
    const int tn  = tid & 63;
    const int wid = tid >> 6;             // 0..7
    const int wm  = wid >> 2;             // 0..1
    const int wn  = wid & 3;              // 0..3
    const int q   = tn >> 4;
    const int cn  = tn & 15;
    const int row0 = blockIdx.x * BM;
    const int cbase = wn * 160 + cn;      // this lane's column for j=0

    // ---- early loads: mask + gumbel fragments (latency hides under the K-loop) ----
    float mrow[4];
    #pragma unroll
    for (int r = 0; r < 4; ++r)
        mrow[r] = (mask[row0 + wm * 16 + 4 * q + r] != 0) ? 1.f : 0.f;

    float g[4][10];
    #pragma unroll
    for (int r = 0; r < 4; ++r) {
        const float* gp = gumbel + (size_t)(row0 + wm * 16 + 4 * q + r) * GV + cbase;
        #pragma unroll
        for (int j = 0; j < 10; ++j) g[r][j] = gp[j * 16];
    }

    // acc init = bias
    f32x4 acc[10];
    #pragma unroll
    for (int j = 0; j < 10; ++j) {
        float b = bias[cbase + j * 16];
        f32x4 c; c[0] = b; c[1] = b; c[2] = b; c[3] = b;
        acc[j] = c;
    }

    // ---- K-loop: pure ushort8 loads + MFMA, no LDS, no barriers ----
    const short* ab = apack + ((size_t)(blockIdx.x * 2 + wm) * NT * 64 + tn) * 8;
    const short* bb = wpack + ((size_t)(wn * 10) * 64 + tn) * 8;

    #pragma unroll 4
    for (int t = 0; t < NT; ++t) {
        short8v a = *(const short8v*)(ab + (size_t)t * 512);
        #pragma unroll
        for (int j = 0; j < 10; ++j) {
            short8v bf = *(const short8v*)(bb + (size_t)t * 20480 + j * 512);
            acc[j] = __builtin_amdgcn_mfma_f32_16x16x32_bf16(a, bf, acc[j], 0, 0, 0);
        }
    }

    // ---- per-row reductions in fragment layout ----
    // lane-local over j (col = cbase + 16j, ascending -> strict '>' keeps first index)
    float zm[4], lm[4]; int zi[4];
    #pragma unroll
    for (int r = 0; r < 4; ++r) {
        float l_ = acc[0][r];
        zm[r] = l_ + g[r][0]; zi[r] = cbase; lm[r] = l_;
        #pragma unroll
        for (int j = 1; j < 10; ++j) {
            float lj = acc[j][r];
            float zj = lj + g[r][j];
            if (zj > zm[r]) { zm[r] = zj; zi[r] = cbase + 16 * j; }
            lm[r] = fmaxf(lm[r], lj);
        }
    }
    // 16-lane butterfly within q-group (d<16 keeps q fixed); tie-break: smaller col
    #pragma unroll
    for (int d = 8; d >= 1; d >>= 1) {
        #pragma unroll
        for (int r = 0; r < 4; ++r) {
            float oz = __shfl_xor(zm[r], d, 64); int oi = __shfl_xor(zi[r], d, 64);
            if (oz > zm[r] || (oz == zm[r] && oi < zi[r])) { zm[r] = oz; zi[r] = oi; }
            lm[r] = fmaxf(lm[r], __shfl_xor(lm[r], d, 64));
        }
    }

    // exchange wave-level stats with group partner (wid^1)
    if (cn == 0) {
        #pragma unroll
        for (int r = 0; r < 4; ++r) {
            float4 e; e.x = zm[r]; e.y = __int_as_float(zi[r]); e.z = lm[r]; e.w = 0.f;
            ex[wid][4 * q + r] = e;
        }
    }
    __syncthreads();
    const int pw = wid ^ 1;
    #pragma unroll
    for (int r = 0; r < 4; ++r) {
        float4 e = ex[pw][4 * q + r];
        float pz = e.x; int pi = __float_as_int(e.y);
        if (pz > zm[r] || (pz == zm[r] && pi < zi[r])) { zm[r] = pz; zi[r] = pi; }
        lm[r] = fmaxf(lm[r], e.z);
    }

    // softmax numerators with group max; wave-level partial sums
    float pm[4][10], ps[4];
    #pragma unroll
    for (int r = 0; r < 4; ++r) {
        ps[r] = 0.f;
        #pragma unroll
        for (int j = 0; j < 10; ++j) {
            float p = __expf(acc[j][r] - lm[r]);
            pm[r][j] = p; ps[r] += p;
        }
    }
    #pragma unroll
    for (int d = 8; d >= 1; d >>= 1)
        #pragma unroll
        for (int r = 0; r < 4; ++r)
            ps[r] += __shfl_xor(ps[r], d, 64);

    if (cn == 0) {
        #pragma unroll
        for (int r = 0; r < 4; ++r) ex2[wid][4 * q + r] = ps[r];
    }
    __syncthreads();
    float inv[4];
    #pragma unroll
    for (int r = 0; r < 4; ++r)
        inv[r] = mrow[r] / (ps[r] + ex2[pw][4 * q + r]);

    // marginal column partials: sum over this wave's 16 rows, then across q (same cn)
    float part[10];
    #pragma unroll
    for (int j = 0; j < 10; ++j) {
        part[j] = pm[0][j] * inv[0] + pm[1][j] * inv[1] + pm[2][j] * inv[2] + pm[3][j] * inv[3];
        part[j] += __shfl_xor(part[j], 16, 64);
        part[j] += __shfl_xor(part[j], 32, 64);
    }
    if (q == 0) {
        #pragma unroll
        for (int j = 0; j < 10; ++j)
            mg[wm * GV + cbase + 16 * j] = part[j];   // wn slices disjoint; wm rows disjoint
    }
    // winning indices -> row table (one wave per group: wn==0 -> g0, wn==2 -> g1)
    if ((wn == 0 || wn == 2) && cn == 0) {
        int grp = wn >> 1;
        #pragma unroll
        for (int r = 0; r < 4; ++r)
            rowtab[wm * 16 + 4 * q + r][grp] = zi[r] - grp * V;
    }
    __syncthreads();

    // ---- marginal atomics, mask count, codevector gather ----
    // NOTE: strided loop — R9 bug was `if (tid < GV)` with 512 threads, dropping cols 512..639.
    for (int c = tid; c < GV; c += 512)
        atomicAdd(&ws[c], mg[c] + mg[GV + c]);
    if (wid == 0) {
        int mr = (tn < BM) ? (mask[row0 + tn] != 0) : 0;
        unsigned long long b = __ballot(mr);
        if (tn == 0) atomicAdd(&ws[GV], (float)__popcll(b));
    }
    {
        const int row = tid >> 4;          // 0..31
        const int six = tid & 15;
        #pragma unroll
        for (int i = 0; i < 4; ++i) {
            int e4  = six + 16 * i;        // 0..63 float4s of the 256-float out row
            int grp = e4 >> 5;
            int off = e4 & 31;
            int idx = rowtab[row][grp];
            float4 vv = ((const float4*)(codevec + ((size_t)grp * V + idx) * DG))[off];
            ((float4*)(out + (size_t)(row0 + row) * (2 * DG)))[e4] = vv;
        }
    }
}

__global__ void gumbel_vq_finalize(const float* __restrict__ ws, float* __restrict__ out)
{
    __shared__ float red[GV];
    int t = threadIdx.x;
    float cnt = ws[GV];
    float p = ws[t] / cnt;
    red[t] = p * logf(p + 1e-7f);
    __syncthreads();
    if (t == 0) {
        float e0 = 0.f, e1 = 0.f;
        for (int i = 0; i < V; ++i)  e0 += red[i];
        for (int i = V; i < GV; ++i) e1 += red[i];
        out[(size_t)N_ROWS * 2 * DG] = expf(-e0) + expf(-e1);
    }
}

extern "C" void kernel_launch(void* const* d_in, const int* in_sizes, int n_in,
                              void* d_out, int out_size, void* d_ws, size_t ws_size,
                              hipStream_t stream)
{
    const float* hidden  = (const float*)d_in[0];
    const int*   mask    = (const int*)  d_in[1];
    const float* gumbel  = (const float*)d_in[2];
    const float* W       = (const float*)d_in[3];
    const float* bias    = (const float*)d_in[4];
    const float* codevec = (const float*)d_in[5];
    float* out = (float*)d_out;
    float* ws  = (float*)d_ws;
    // ws layout: [0..639] marginal, [640] mask count, +4096B: W bf16 fragment pack (655 KB).
    // A bf16 fragment pack (33,554,432 B) lives in the OUT buffer (fits; barrier-ordered:
    // each block reads only its own rows' apack before its barriers, writes out after;
    // per-row byte ranges of apack and out coincide, so blocks never alias each other).
    short* wpack = (short*)((char*)d_ws + 4096);
    short* apack = (short*)d_out;

    hipMemsetAsync(d_ws, 0, (GV + 1) * sizeof(float), stream);
    pack_w<<<160, 256, 0, stream>>>(W, wpack);
    pack_a<<<8192, 256, 0, stream>>>(hidden, apack);
    gumbel_vq_main<<<N_ROWS / BM, 512, 0, stream>>>(apack, mask, gumbel, wpack, bias, codevec, out, ws);
    gumbel_vq_finalize<<<1, GV, 0, stream>>>(ws, out);
}

// Round 11
// 115.988 us; speedup vs baseline: 1.2889x; 1.2889x over previous
//
#include <hip/hip_runtime.h>
#include <hip/hip_bf16.h>
#include <math.h>

#define N_ROWS 32768
#define H      512
#define GV     640
#define V      320
#define DG     128
#define BM     32           // rows per block
#define NT     16           // K-steps of 32 (H=512)

typedef __attribute__((ext_vector_type(4))) float f32x4;
typedef __attribute__((ext_vector_type(8))) short short8v;   // 8 bf16

static __device__ __forceinline__ short f2bf(float f) {      // fp32 -> bf16 RNE
    unsigned int u = __float_as_uint(f);
    u += 0x7fffu + ((u >> 16) & 1u);
    return (short)(u >> 16);
}

// Pack W (fp32 [512][640]) into bf16 B-fragments for mfma_f32_16x16x32_bf16:
// frag (t, ct): lane l supplies B[k = t*32 + 8*(l>>4) + i][col = ct*16 + (l&15)], i=0..7.
// wp[(((t*40 + ct)*64 + l)*8 + i)] -> main-kernel B-load = 1 coalesced ushort8.
__global__ __launch_bounds__(256)
void pack_w(const float* __restrict__ W, short* __restrict__ wp)
{
    int gid = blockIdx.x * 256 + threadIdx.x;   // 40960 = 16 t * 40 ct * 64 l
    int l   = gid & 63;
    int ct  = (gid >> 6) % 40;
    int t   = gid / (40 * 64);
    int row = t * 32 + 8 * (l >> 4);
    int col = ct * 16 + (l & 15);
    short8v pk;
    #pragma unroll
    for (int i = 0; i < 8; ++i)
        pk[i] = f2bf(W[(size_t)(row + i) * GV + col]);
    *(short8v*)(wp + (size_t)gid * 8) = pk;
}

// Pack hidden (fp32 [32768][512]) into bf16 A-fragments, stored in the OUT buffer.
// frag (rt, t): lane l supplies A[row = rt*16 + (l&15)][k = t*32 + 8*(l>>4) + i], i=0..7.
__global__ __launch_bounds__(256)
void pack_a(const float* __restrict__ hidden, short* __restrict__ ap)
{
    int gid = blockIdx.x * 256 + threadIdx.x;   // 2,097,152 = 2048 rt * 16 t * 64 l
    int l   = gid & 63;
    int t   = (gid >> 6) & 15;
    int rt  = gid >> 10;
    const float* src = hidden + (size_t)(rt * 16 + (l & 15)) * H + t * 32 + 8 * (l >> 4);
    float4 x0 = *(const float4*)src;
    float4 x1 = *(const float4*)(src + 4);
    short8v pk;
    pk[0] = f2bf(x0.x); pk[1] = f2bf(x0.y); pk[2] = f2bf(x0.z); pk[3] = f2bf(x0.w);
    pk[4] = f2bf(x1.x); pk[5] = f2bf(x1.y); pk[6] = f2bf(x1.z); pk[7] = f2bf(x1.w);
    *(short8v*)(ap + (size_t)gid * 8) = pk;
}

// Fused: bf16-MFMA logits GEMM + gumbel argmax + softmax marginal + codevector gather.
// 512 threads = 8 waves, wave grid 2(M) x 4(N). Epilogue reduces in C-fragment layout
// (lane (q,cn) holds rows 4q+r): 10-chain local + 4-step 16-lane butterfly, partner
// exchange via tiny LDS. CRITICAL (R10 lesson): gumbel/mask loads are issued AFTER the
// K-loop — vmcnt completion is IN-ORDER, so any load issued before the K-loop makes
// every MFMA's B-operand wait transitively on all ~44 cold-HBM gumbel loads (R10: 130us,
// MfmaUtil 6%). The g-independent lm-reduction runs while g-loads are in flight.
__global__ __launch_bounds__(512, 4)
void gumbel_vq_main(const short* apack,               // aliases out! (no restrict)
                    const int*   __restrict__ mask,
                    const float* __restrict__ gumbel,
                    const short* __restrict__ wpack,
                    const float* __restrict__ bias,
                    const float* __restrict__ codevec,
                    float* out,                       // aliases apack (no restrict)
                    float* __restrict__ ws)
{
    __shared__ float4 ex[8][16];          // per-wave per-row (zmax, zidx, lmax, -)
    __shared__ float  ex2[8][16];         // per-wave per-row psum
    __shared__ float  mg[2 * GV];         // per-wm marginal partials
    __shared__ int    rowtab[BM][2];      // winning codevector idx per row per group

    const int tid = threadIdx.x;
    const int tn  = tid & 63;
    const int wid = tid >> 6;             // 0..7
    const int wm  = wid >> 2;             // 0..1
    const int wn  = wid & 3;              // 0..3
    const int q   = tn >> 4;
    const int cn  = tn & 15;
    const int row0 = blockIdx.x * BM;
    const int cbase = wn * 160 + cn;      // this lane's column for j=0

    // acc init = bias
    f32x4 acc[10];
    #pragma unroll
    for (int j = 0; j < 10; ++j) {
        float b = bias[cbase + j * 16];
        f32x4 c; c[0] = b; c[1] = b; c[2] = b; c[3] = b;
        acc[j] = c;
    }

    // ---- K-loop: pure ushort8 loads + MFMA, no LDS, no barriers, no cold loads ahead ----
    const short* ab = apack + ((size_t)(blockIdx.x * 2 + wm) * NT * 64 + tn) * 8;
    const short* bb = wpack + ((size_t)(wn * 10) * 64 + tn) * 8;

    #pragma unroll 4
    for (int t = 0; t < NT; ++t) {
        short8v a = *(const short8v*)(ab + (size_t)t * 512);
        #pragma unroll
        for (int j = 0; j < 10; ++j) {
            short8v bf = *(const short8v*)(bb + (size_t)t * 20480 + j * 512);
            acc[j] = __builtin_amdgcn_mfma_f32_16x16x32_bf16(a, bf, acc[j], 0, 0, 0);
        }
    }

    // ---- NOW issue gumbel + mask loads (fragment layout); lm-reduction covers them ----
    float g[4][10];
    #pragma unroll
    for (int r = 0; r < 4; ++r) {
        const float* gp = gumbel + (size_t)(row0 + wm * 16 + 4 * q + r) * GV + cbase;
        #pragma unroll
        for (int j = 0; j < 10; ++j) g[r][j] = gp[j * 16];
    }
    float mrow[4];
    #pragma unroll
    for (int r = 0; r < 4; ++r)
        mrow[r] = (mask[row0 + wm * 16 + 4 * q + r] != 0) ? 1.f : 0.f;

    // g-independent: plain-logit max, local chain + 16-lane butterfly
    float lm[4];
    #pragma unroll
    for (int r = 0; r < 4; ++r) {
        lm[r] = acc[0][r];
        #pragma unroll
        for (int j = 1; j < 10; ++j) lm[r] = fmaxf(lm[r], acc[j][r]);
    }
    #pragma unroll
    for (int d = 8; d >= 1; d >>= 1)
        #pragma unroll
        for (int r = 0; r < 4; ++r)
            lm[r] = fmaxf(lm[r], __shfl_xor(lm[r], d, 64));

    // g-dependent: argmax of logits+gumbel (col = cbase+16j ascending -> '>' keeps first idx)
    float zm[4]; int zi[4];
    #pragma unroll
    for (int r = 0; r < 4; ++r) {
        zm[r] = acc[0][r] + g[r][0]; zi[r] = cbase;
        #pragma unroll
        for (int j = 1; j < 10; ++j) {
            float zj = acc[j][r] + g[r][j];
            if (zj > zm[r]) { zm[r] = zj; zi[r] = cbase + 16 * j; }
        }
    }
    #pragma unroll
    for (int d = 8; d >= 1; d >>= 1) {
        #pragma unroll
        for (int r = 0; r < 4; ++r) {
            float oz = __shfl_xor(zm[r], d, 64); int oi = __shfl_xor(zi[r], d, 64);
            if (oz > zm[r] || (oz == zm[r] && oi < zi[r])) { zm[r] = oz; zi[r] = oi; }
        }
    }

    // exchange wave-level stats with group partner (wid^1)
    if (cn == 0) {
        #pragma unroll
        for (int r = 0; r < 4; ++r) {
            float4 e; e.x = zm[r]; e.y = __int_as_float(zi[r]); e.z = lm[r]; e.w = 0.f;
            ex[wid][4 * q + r] = e;
        }
    }
    __syncthreads();
    const int pw = wid ^ 1;
    #pragma unroll
    for (int r = 0; r < 4; ++r) {
        float4 e = ex[pw][4 * q + r];
        float pz = e.x; int pi = __float_as_int(e.y);
        if (pz > zm[r] || (pz == zm[r] && pi < zi[r])) { zm[r] = pz; zi[r] = pi; }
        lm[r] = fmaxf(lm[r], e.z);
    }

    // softmax numerators with group max; wave-level partial sums
    float pm[4][10], ps[4];
    #pragma unroll
    for (int r = 0; r < 4; ++r) {
        ps[r] = 0.f;
        #pragma unroll
        for (int j = 0; j < 10; ++j) {
            float p = __expf(acc[j][r] - lm[r]);
            pm[r][j] = p; ps[r] += p;
        }
    }
    #pragma unroll
    for (int d = 8; d >= 1; d >>= 1)
        #pragma unroll
        for (int r = 0; r < 4; ++r)
            ps[r] += __shfl_xor(ps[r], d, 64);

    if (cn == 0) {
        #pragma unroll
        for (int r = 0; r < 4; ++r) ex2[wid][4 * q + r] = ps[r];
    }
    __syncthreads();
    float inv[4];
    #pragma unroll
    for (int r = 0; r < 4; ++r)
        inv[r] = mrow[r] / (ps[r] + ex2[pw][4 * q + r]);

    // marginal column partials: sum over this wave's 16 rows, then across q (same cn)
    float part[10];
    #pragma unroll
    for (int j = 0; j < 10; ++j) {
        part[j] = pm[0][j] * inv[0] + pm[1][j] * inv[1] + pm[2][j] * inv[2] + pm[3][j] * inv[3];
        part[j] += __shfl_xor(part[j], 16, 64);
        part[j] += __shfl_xor(part[j], 32, 64);
    }
    if (q == 0) {
        #pragma unroll
        for (int j = 0; j < 10; ++j)
            mg[wm * GV + cbase + 16 * j] = part[j];   // wn slices disjoint; wm rows disjoint
    }
    // winning indices -> row table (one wave per group: wn==0 -> g0, wn==2 -> g1)
    if ((wn == 0 || wn == 2) && cn == 0) {
        int grp = wn >> 1;
        #pragma unroll
        for (int r = 0; r < 4; ++r)
            rowtab[wm * 16 + 4 * q + r][grp] = zi[r] - grp * V;
    }
    __syncthreads();

    // ---- marginal atomics, mask count, codevector gather ----
    for (int c = tid; c < GV; c += 512)
        atomicAdd(&ws[c], mg[c] + mg[GV + c]);
    if (wid == 0) {
        int mr = (tn < BM) ? (mask[row0 + tn] != 0) : 0;
        unsigned long long b = __ballot(mr);
        if (tn == 0) atomicAdd(&ws[GV], (float)__popcll(b));
    }
    {
        const int row = tid >> 4;          // 0..31
        const int six = tid & 15;
        #pragma unroll
        for (int i = 0; i < 4; ++i) {
            int e4  = six + 16 * i;        // 0..63 float4s of the 256-float out row
            int grp = e4 >> 5;
            int off = e4 & 31;
            int idx = rowtab[row][grp];
            float4 vv = ((const float4*)(codevec + ((size_t)grp * V + idx) * DG))[off];
            ((float4*)(out + (size_t)(row0 + row) * (2 * DG)))[e4] = vv;
        }
    }
}

__global__ void gumbel_vq_finalize(const float* __restrict__ ws, float* __restrict__ out)
{
    __shared__ float red[GV];
    int t = threadIdx.x;
    float cnt = ws[GV];
    float p = ws[t] / cnt;
    red[t] = p * logf(p + 1e-7f);
    __syncthreads();
    if (t == 0) {
        float e0 = 0.f, e1 = 0.f;
        for (int i = 0; i < V; ++i)  e0 += red[i];
        for (int i = V; i < GV; ++i) e1 += red[i];
        out[(size_t)N_ROWS * 2 * DG] = expf(-e0) + expf(-e1);
    }
}

extern "C" void kernel_launch(void* const* d_in, const int* in_sizes, int n_in,
                              void* d_out, int out_size, void* d_ws, size_t ws_size,
                              hipStream_t stream)
{
    const float* hidden  = (const float*)d_in[0];
    const int*   mask    = (const int*)  d_in[1];
    const float* gumbel  = (const float*)d_in[2];
    const float* W       = (const float*)d_in[3];
    const float* bias    = (const float*)d_in[4];
    const float* codevec = (const float*)d_in[5];
    float* out = (float*)d_out;
    float* ws  = (float*)d_ws;
    // ws layout: [0..639] marginal, [640] mask count, +4096B: W bf16 fragment pack (655 KB).
    // A bf16 fragment pack (33,554,432 B) lives in the OUT buffer (fits; barrier-ordered:
    // each block reads only its own rows' apack before its barriers, writes out after;
    // per-row byte ranges of apack and out coincide, so blocks never alias each other).
    short* wpack = (short*)((char*)d_ws + 4096);
    short* apack = (short*)d_out;

    hipMemsetAsync(d_ws, 0, (GV + 1) * sizeof(float), stream);
    pack_w<<<160, 256, 0, stream>>>(W, wpack);
    pack_a<<<8192, 256, 0, stream>>>(hidden, apack);
    gumbel_vq_main<<<N_ROWS / BM, 512, 0, stream>>>(apack, mask, gumbel, wpack, bias, codevec, out, ws);
    gumbel_vq_finalize<<<1, GV, 0, stream>>>(ws, out);
}

// Round 12
// 112.431 us; speedup vs baseline: 1.3297x; 1.0316x over previous
//
#include <hip/hip_runtime.h>
#include <hip/hip_bf16.h>
#include <math.h>

#define N_ROWS 32768
#define H      512
#define GV     640
#define V      320
#define DG     128
#define BM     32           // rows per block
#define NT     16           // K-steps of 32 (H=512)

typedef __attribute__((ext_vector_type(4))) float f32x4;
typedef __attribute__((ext_vector_type(8))) short short8v;   // 8 bf16

static __device__ __forceinline__ short f2bf(float f) {      // fp32 -> bf16 RNE
    unsigned int u = __float_as_uint(f);
    u += 0x7fffu + ((u >> 16) & 1u);
    return (short)(u >> 16);
}

// Pack W (fp32 [512][640]) into bf16 B-fragments for mfma_f32_16x16x32_bf16:
// frag (t, ct): lane l supplies B[k = t*32 + 8*(l>>4) + i][col = ct*16 + (l&15)], i=0..7.
// wp[(((t*40 + ct)*64 + l)*8 + i)] -> main-kernel B-load = 1 coalesced ushort8.
__global__ __launch_bounds__(256)
void pack_w(const float* __restrict__ W, short* __restrict__ wp)
{
    int gid = blockIdx.x * 256 + threadIdx.x;   // 40960 = 16 t * 40 ct * 64 l
    int l   = gid & 63;
    int ct  = (gid >> 6) % 40;
    int t   = gid / (40 * 64);
    int row = t * 32 + 8 * (l >> 4);
    int col = ct * 16 + (l & 15);
    short8v pk;
    #pragma unroll
    for (int i = 0; i < 8; ++i)
        pk[i] = f2bf(W[(size_t)(row + i) * GV + col]);
    *(short8v*)(wp + (size_t)gid * 8) = pk;
}

// Pack hidden (fp32 [32768][512]) into bf16 A-fragments, stored in the OUT buffer.
// frag (rt, t): lane l supplies A[row = rt*16 + (l&15)][k = t*32 + 8*(l>>4) + i], i=0..7.
__global__ __launch_bounds__(256)
void pack_a(const float* __restrict__ hidden, short* __restrict__ ap)
{
    int gid = blockIdx.x * 256 + threadIdx.x;   // 2,097,152 = 2048 rt * 16 t * 64 l
    int l   = gid & 63;
    int t   = (gid >> 6) & 15;
    int rt  = gid >> 10;
    const float* src = hidden + (size_t)(rt * 16 + (l & 15)) * H + t * 32 + 8 * (l >> 4);
    float4 x0 = *(const float4*)src;
    float4 x1 = *(const float4*)(src + 4);
    short8v pk;
    pk[0] = f2bf(x0.x); pk[1] = f2bf(x0.y); pk[2] = f2bf(x0.z); pk[3] = f2bf(x0.w);
    pk[4] = f2bf(x1.x); pk[5] = f2bf(x1.y); pk[6] = f2bf(x1.z); pk[7] = f2bf(x1.w);
    *(short8v*)(ap + (size_t)gid * 8) = pk;
}

// Fused: bf16-MFMA logits GEMM + gumbel argmax + softmax marginal + codevector gather.
// 512 threads = 8 waves, wave grid 2(M) x 4(N). K-loop is REGISTER DOUBLE-BUFFERED:
// R11's VGPR=60 proved the compiler pipelined nothing — each of the 160 B-loads exposed
// ~200cy L2 latency (MfmaUtil 9%). Explicit prefetch of step t+1's A+B frags into a
// second register set (all indices static after full unroll) forces in-flight loads;
// step t's MFMAs cover step t+1's load latency. Gumbel/mask loads stay AFTER the K-loop
// (R10 lesson: vmcnt is in-order; cold loads ahead of the K-loop serialize every MFMA).
__global__ __launch_bounds__(512, 3)
void gumbel_vq_main(const short* apack,               // aliases out! (no restrict)
                    const int*   __restrict__ mask,
                    const float* __restrict__ gumbel,
                    const short* __restrict__ wpack,
                    const float* __restrict__ bias,
                    const float* __restrict__ codevec,
                    float* out,                       // aliases apack (no restrict)
                    float* __restrict__ ws)
{
    __shared__ float4 ex[8][16];          // per-wave per-row (zmax, zidx, lmax, -)
    __shared__ float  ex2[8][16];         // per-wave per-row psum
    __shared__ float  mg[2 * GV];         // per-wm marginal partials
    __shared__ int    rowtab[BM][2];      // winning codevector idx per row per group

    const int tid = threadIdx.x;
    const int tn  = tid & 63;
    const int wid = tid >> 6;             // 0..7
    const int wm  = wid >> 2;             // 0..1
    const int wn  = wid & 3;              // 0..3
    const int q   = tn >> 4;
    const int cn  = tn & 15;
    const int row0 = blockIdx.x * BM;
    const int cbase = wn * 160 + cn;      // this lane's column for j=0

    // acc init = bias
    f32x4 acc[10];
    #pragma unroll
    for (int j = 0; j < 10; ++j) {
        float b = bias[cbase + j * 16];
        f32x4 c; c[0] = b; c[1] = b; c[2] = b; c[3] = b;
        acc[j] = c;
    }

    // ---- K-loop: register double-buffered ushort8 loads + MFMA ----
    const short* ab = apack + ((size_t)(blockIdx.x * 2 + wm) * NT * 64 + tn) * 8;
    const short* bb = wpack + ((size_t)(wn * 10) * 64 + tn) * 8;

    short8v aB[2], bB[2][10];
    aB[0] = *(const short8v*)ab;
    #pragma unroll
    for (int j = 0; j < 10; ++j)
        bB[0][j] = *(const short8v*)(bb + j * 512);

    #pragma unroll
    for (int t = 0; t < NT; ++t) {
        const int cur = t & 1, nxt = cur ^ 1;
        if (t < NT - 1) {                 // prefetch step t+1 while step t computes
            aB[nxt] = *(const short8v*)(ab + (size_t)(t + 1) * 512);
            #pragma unroll
            for (int j = 0; j < 10; ++j)
                bB[nxt][j] = *(const short8v*)(bb + (size_t)(t + 1) * 20480 + j * 512);
        }
        #pragma unroll
        for (int j = 0; j < 10; ++j)
            acc[j] = __builtin_amdgcn_mfma_f32_16x16x32_bf16(aB[cur], bB[cur][j], acc[j], 0, 0, 0);
    }

    // ---- NOW issue gumbel + mask loads (fragment layout); lm-reduction covers them ----
    float g[4][10];
    #pragma unroll
    for (int r = 0; r < 4; ++r) {
        const float* gp = gumbel + (size_t)(row0 + wm * 16 + 4 * q + r) * GV + cbase;
        #pragma unroll
        for (int j = 0; j < 10; ++j) g[r][j] = gp[j * 16];
    }
    float mrow[4];
    #pragma unroll
    for (int r = 0; r < 4; ++r)
        mrow[r] = (mask[row0 + wm * 16 + 4 * q + r] != 0) ? 1.f : 0.f;

    // g-independent: plain-logit max, local chain + 16-lane butterfly
    float lm[4];
    #pragma unroll
    for (int r = 0; r < 4; ++r) {
        lm[r] = acc[0][r];
        #pragma unroll
        for (int j = 1; j < 10; ++j) lm[r] = fmaxf(lm[r], acc[j][r]);
    }
    #pragma unroll
    for (int d = 8; d >= 1; d >>= 1)
        #pragma unroll
        for (int r = 0; r < 4; ++r)
            lm[r] = fmaxf(lm[r], __shfl_xor(lm[r], d, 64));

    // g-dependent: argmax of logits+gumbel (col = cbase+16j ascending -> '>' keeps first idx)
    float zm[4]; int zi[4];
    #pragma unroll
    for (int r = 0; r < 4; ++r) {
        zm[r] = acc[0][r] + g[r][0]; zi[r] = cbase;
        #pragma unroll
        for (int j = 1; j < 10; ++j) {
            float zj = acc[j][r] + g[r][j];
            if (zj > zm[r]) { zm[r] = zj; zi[r] = cbase + 16 * j; }
        }
    }
    #pragma unroll
    for (int d = 8; d >= 1; d >>= 1) {
        #pragma unroll
        for (int r = 0; r < 4; ++r) {
            float oz = __shfl_xor(zm[r], d, 64); int oi = __shfl_xor(zi[r], d, 64);
            if (oz > zm[r] || (oz == zm[r] && oi < zi[r])) { zm[r] = oz; zi[r] = oi; }
        }
    }

    // exchange wave-level stats with group partner (wid^1)
    if (cn == 0) {
        #pragma unroll
        for (int r = 0; r < 4; ++r) {
            float4 e; e.x = zm[r]; e.y = __int_as_float(zi[r]); e.z = lm[r]; e.w = 0.f;
            ex[wid][4 * q + r] = e;
        }
    }
    __syncthreads();
    const int pw = wid ^ 1;
    #pragma unroll
    for (int r = 0; r < 4; ++r) {
        float4 e = ex[pw][4 * q + r];
        float pz = e.x; int pi = __float_as_int(e.y);
        if (pz > zm[r] || (pz == zm[r] && pi < zi[r])) { zm[r] = pz; zi[r] = pi; }
        lm[r] = fmaxf(lm[r], e.z);
    }

    // softmax numerators with group max; wave-level partial sums
    float pm[4][10], ps[4];
    #pragma unroll
    for (int r = 0; r < 4; ++r) {
        ps[r] = 0.f;
        #pragma unroll
        for (int j = 0; j < 10; ++j) {
            float p = __expf(acc[j][r] - lm[r]);
            pm[r][j] = p; ps[r] += p;
        }
    }
    #pragma unroll
    for (int d = 8; d >= 1; d >>= 1)
        #pragma unroll
        for (int r = 0; r < 4; ++r)
            ps[r] += __shfl_xor(ps[r], d, 64);

    if (cn == 0) {
        #pragma unroll
        for (int r = 0; r < 4; ++r) ex2[wid][4 * q + r] = ps[r];
    }
    __syncthreads();
    float inv[4];
    #pragma unroll
    for (int r = 0; r < 4; ++r)
        inv[r] = mrow[r] / (ps[r] + ex2[pw][4 * q + r]);

    // marginal column partials: sum over this wave's 16 rows, then across q (same cn)
    float part[10];
    #pragma unroll
    for (int j = 0; j < 10; ++j) {
        part[j] = pm[0][j] * inv[0] + pm[1][j] * inv[1] + pm[2][j] * inv[2] + pm[3][j] * inv[3];
        part[j] += __shfl_xor(part[j], 16, 64);
        part[j] += __shfl_xor(part[j], 32, 64);
    }
    if (q == 0) {
        #pragma unroll
        for (int j = 0; j < 10; ++j)
            mg[wm * GV + cbase + 16 * j] = part[j];   // wn slices disjoint; wm rows disjoint
    }
    // winning indices -> row table (one wave per group: wn==0 -> g0, wn==2 -> g1)
    if ((wn == 0 || wn == 2) && cn == 0) {
        int grp = wn >> 1;
        #pragma unroll
        for (int r = 0; r < 4; ++r)
            rowtab[wm * 16 + 4 * q + r][grp] = zi[r] - grp * V;
    }
    __syncthreads();

    // ---- marginal atomics, mask count, codevector gather ----
    for (int c = tid; c < GV; c += 512)
        atomicAdd(&ws[c], mg[c] + mg[GV + c]);
    if (wid == 0) {
        int mr = (tn < BM) ? (mask[row0 + tn] != 0) : 0;
        unsigned long long b = __ballot(mr);
        if (tn == 0) atomicAdd(&ws[GV], (float)__popcll(b));
    }
    {
        const int row = tid >> 4;          // 0..31
        const int six = tid & 15;
        #pragma unroll
        for (int i = 0; i < 4; ++i) {
            int e4  = six + 16 * i;        // 0..63 float4s of the 256-float out row
            int grp = e4 >> 5;
            int off = e4 & 31;
            int idx = rowtab[row][grp];
            float4 vv = ((const float4*)(codevec + ((size_t)grp * V + idx) * DG))[off];
            ((float4*)(out + (size_t)(row0 + row) * (2 * DG)))[e4] = vv;
        }
    }
}

__global__ void gumbel_vq_finalize(const float* __restrict__ ws, float* __restrict__ out)
{
    __shared__ float red[GV];
    int t = threadIdx.x;
    float cnt = ws[GV];
    float p = ws[t] / cnt;
    red[t] = p * logf(p + 1e-7f);
    __syncthreads();
    if (t == 0) {
        float e0 = 0.f, e1 = 0.f;
        for (int i = 0; i < V; ++i)  e0 += red[i];
        for (int i = V; i < GV; ++i) e1 += red[i];
        out[(size_t)N_ROWS * 2 * DG] = expf(-e0) + expf(-e1);
    }
}

extern "C" void kernel_launch(void* const* d_in, const int* in_sizes, int n_in,
                              void* d_out, int out_size, void* d_ws, size_t ws_size,
                              hipStream_t stream)
{
    const float* hidden  = (const float*)d_in[0];
    const int*   mask    = (const int*)  d_in[1];
    const float* gumbel  = (const float*)d_in[2];
    const float* W       = (const float*)d_in[3];
    const float* bias    = (const float*)d_in[4];
    const float* codevec = (const float*)d_in[5];
    float* out = (float*)d_out;
    float* ws  = (float*)d_ws;
    // ws layout: [0..639] marginal, [640] mask count, +4096B: W bf16 fragment pack (655 KB).
    // A bf16 fragment pack (33,554,432 B) lives in the OUT buffer (fits; barrier-ordered:
    // each block reads only its own rows' apack before its barriers, writes out after;
    // per-row byte ranges of apack and out coincide, so blocks never alias each other).
    short* wpack = (short*)((char*)d_ws + 4096);
    short* apack = (short*)d_out;

    hipMemsetAsync(d_ws, 0, (GV + 1) * sizeof(float), stream);
    pack_w<<<160, 256, 0, stream>>>(W, wpack);
    pack_a<<<8192, 256, 0, stream>>>(hidden, apack);
    gumbel_vq_main<<<N_ROWS / BM, 512, 0, stream>>>(apack, mask, gumbel, wpack, bias, codevec, out, ws);
    gumbel_vq_finalize<<<1, GV, 0, stream>>>(ws, out);
}

// Round 13
// 102.356 us; speedup vs baseline: 1.4606x; 1.0984x over previous
//
#include <hip/hip_runtime.h>
#include <hip/hip_bf16.h>
#include <math.h>

#define N_ROWS 32768
#define H      512
#define GV     640
#define V      320
#define DG     128
#define BM     32           // rows per block
#define NT     16           // K-steps of 32 (H=512)

typedef __attribute__((ext_vector_type(4))) float f32x4;
typedef __attribute__((ext_vector_type(8))) short short8v;   // 8 bf16

static __device__ __forceinline__ short f2bf(float f) {      // fp32 -> bf16 RNE
    unsigned int u = __float_as_uint(f);
    u += 0x7fffu + ((u >> 16) & 1u);
    return (short)(u >> 16);
}

// Pack W (fp32 [512][640]) into bf16 B-fragments for mfma_f32_16x16x32_bf16:
// frag (t, ct): lane l supplies B[k = t*32 + 8*(l>>4) + i][col = ct*16 + (l&15)], i=0..7.
// wp[(((t*40 + ct)*64 + l)*8 + i)] -> step t's 40 KB slice is CONTIGUOUS (linear LDS staging).
__global__ __launch_bounds__(256)
void pack_w(const float* __restrict__ W, short* __restrict__ wp)
{
    int gid = blockIdx.x * 256 + threadIdx.x;   // 40960 = 16 t * 40 ct * 64 l
    int l   = gid & 63;
    int ct  = (gid >> 6) % 40;
    int t   = gid / (40 * 64);
    int row = t * 32 + 8 * (l >> 4);
    int col = ct * 16 + (l & 15);
    short8v pk;
    #pragma unroll
    for (int i = 0; i < 8; ++i)
        pk[i] = f2bf(W[(size_t)(row + i) * GV + col]);
    *(short8v*)(wp + (size_t)gid * 8) = pk;
}

// Pack hidden (fp32 [32768][512]) into bf16 A-fragments, stored in the OUT buffer.
// frag (rt, t): lane l supplies A[row = rt*16 + (l&15)][k = t*32 + 8*(l>>4) + i], i=0..7.
__global__ __launch_bounds__(256)
void pack_a(const float* __restrict__ hidden, short* __restrict__ ap)
{
    int gid = blockIdx.x * 256 + threadIdx.x;   // 2,097,152 = 2048 rt * 16 t * 64 l
    int l   = gid & 63;
    int t   = (gid >> 6) & 15;
    int rt  = gid >> 10;
    const float* src = hidden + (size_t)(rt * 16 + (l & 15)) * H + t * 32 + 8 * (l >> 4);
    float4 x0 = *(const float4*)src;
    float4 x1 = *(const float4*)(src + 4);
    short8v pk;
    pk[0] = f2bf(x0.x); pk[1] = f2bf(x0.y); pk[2] = f2bf(x0.z); pk[3] = f2bf(x0.w);
    pk[4] = f2bf(x1.x); pk[5] = f2bf(x1.y); pk[6] = f2bf(x1.z); pk[7] = f2bf(x1.w);
    *(short8v*)(ap + (size_t)gid * 8) = pk;
}

// Fused: bf16-MFMA logits GEMM + gumbel argmax + softmax marginal + codevector gather.
// 512 threads = 8 waves, wave grid 2(M) x 4(N). K-loop: LDS 2-phase double-buffered W
// staging (T3 minimal + T14 issue-early/write-late). R11/R12 showed the compiler refuses
// to keep VMEM loads in flight in a pure-register loop (VGPR 56-60, MfmaUtil 9%); the
// barrier-structured LDS pipeline makes the overlap structural — loads for step t+1 issue
// at iter-t top, their L2 latency elapses under 10 ds_read_b128 + 10 MFMAs, and
// __syncthreads() prevents the scheduler from sinking them. Gumbel/mask loads stay AFTER
// the K-loop (R10: vmcnt is in-order; cold loads ahead serialize every MFMA).
__global__ __launch_bounds__(512, 4)
void gumbel_vq_main(const short* apack,               // aliases out! (no restrict)
                    const int*   __restrict__ mask,
                    const float* __restrict__ gumbel,
                    const short* __restrict__ wpack,
                    const float* __restrict__ bias,
                    const float* __restrict__ codevec,
                    float* out,                       // aliases apack (no restrict)
                    float* __restrict__ ws)
{
    // 2 x 40KB staging buffers = 81920 B exactly -> exactly 2 blocks/CU (160 KB LDS).
    __shared__ __align__(16) short sbuf[2][20480];
    // Epilogue structures ALIAS buffer 0 (bytes 0..7935): used only after the K-loop's
    // final barrier; the last K-iteration reads only sbuf[1] (t=15 -> cur=1) — disjoint.
    float4 (*ex)[16]  = (float4 (*)[16])(&sbuf[0][0]);           //  2048 B: per-wave (zm,zi,lm)
    float*  ex2       = (float*)((char*)sbuf + 2048);            //   512 B: per-wave psum
    float*  mg        = (float*)((char*)sbuf + 2560);            //  5120 B: per-wm marginals
    int   (*rowtab)[2] = (int (*)[2])((char*)sbuf + 7680);       //   256 B: winner idx/row/group

    const int tid = threadIdx.x;
    const int tn  = tid & 63;
    const int wid = tid >> 6;             // 0..7
    const int wm  = wid >> 2;             // 0..1
    const int wn  = wid & 3;              // 0..3
    const int q   = tn >> 4;
    const int cn  = tn & 15;
    const int row0 = blockIdx.x * BM;
    const int cbase = wn * 160 + cn;      // this lane's column for j=0

    // acc init = bias
    f32x4 acc[10];
    #pragma unroll
    for (int j = 0; j < 10; ++j) {
        float b = bias[cbase + j * 16];
        f32x4 c; c[0] = b; c[1] = b; c[2] = b; c[3] = b;
        acc[j] = c;
    }

    const short* ab = apack + ((size_t)(blockIdx.x * 2 + wm) * NT * 64 + tn) * 8;

    // ---- prologue: stage K-step 0 into sbuf[0]; load A(0) ----
    {
        const short* wt = wpack;          // step 0 slice (40960 B contiguous)
        short8v s0 = *(const short8v*)(wt + (size_t)(tid +    0) * 8);
        short8v s1 = *(const short8v*)(wt + (size_t)(tid +  512) * 8);
        short8v s2 = *(const short8v*)(wt + (size_t)(tid + 1024) * 8);
        short8v s3 = *(const short8v*)(wt + (size_t)(tid + 1536) * 8);
        short8v s4 = *(const short8v*)(wt + (size_t)(tid + 2048) * 8);
        short* bd = &sbuf[0][(size_t)tid * 8];
        *(short8v*)(bd +     0) = s0;
        *(short8v*)(bd +  4096) = s1;     // 512*8 shorts
        *(short8v*)(bd +  8192) = s2;
        *(short8v*)(bd + 12288) = s3;
        *(short8v*)(bd + 16384) = s4;
    }
    short8v areg = *(const short8v*)ab;
    __syncthreads();

    // ---- K-loop: 2-phase LDS pipeline ----
    #pragma unroll
    for (int t = 0; t < NT; ++t) {
        const int cur = t & 1;
        short8v s0, s1, s2, s3, s4, anx;
        if (t + 1 < NT) {                 // issue-early: loads for step t+1
            const short* wt = wpack + (size_t)(t + 1) * 20480;
            s0 = *(const short8v*)(wt + (size_t)(tid +    0) * 8);
            s1 = *(const short8v*)(wt + (size_t)(tid +  512) * 8);
            s2 = *(const short8v*)(wt + (size_t)(tid + 1024) * 8);
            s3 = *(const short8v*)(wt + (size_t)(tid + 1536) * 8);
            s4 = *(const short8v*)(wt + (size_t)(tid + 2048) * 8);
            anx = *(const short8v*)(ab + (size_t)(t + 1) * 512);
        }
        // consume step t: 10 ds_read_b128 + 10 MFMA (covers the staging-load latency)
        const short* bufc = &sbuf[cur][(size_t)(wn * 640 + tn) * 8];
        #pragma unroll
        for (int j = 0; j < 10; ++j) {
            short8v bf = *(const short8v*)(bufc + j * 512);
            acc[j] = __builtin_amdgcn_mfma_f32_16x16x32_bf16(areg, bf, acc[j], 0, 0, 0);
        }
        if (t + 1 < NT) {                 // write-late: reg -> LDS for step t+1
            short* bd = &sbuf[cur ^ 1][(size_t)tid * 8];
            *(short8v*)(bd +     0) = s0;
            *(short8v*)(bd +  4096) = s1;
            *(short8v*)(bd +  8192) = s2;
            *(short8v*)(bd + 12288) = s3;
            *(short8v*)(bd + 16384) = s4;
            areg = anx;
        }
        __syncthreads();                  // structural: loads can't sink across this
    }

    // ---- NOW issue gumbel + mask loads (fragment layout); lm-reduction covers them ----
    float g[4][10];
    #pragma unroll
    for (int r = 0; r < 4; ++r) {
        const float* gp = gumbel + (size_t)(row0 + wm * 16 + 4 * q + r) * GV + cbase;
        #pragma unroll
        for (int j = 0; j < 10; ++j) g[r][j] = gp[j * 16];
    }
    float mrow[4];
    #pragma unroll
    for (int r = 0; r < 4; ++r)
        mrow[r] = (mask[row0 + wm * 16 + 4 * q + r] != 0) ? 1.f : 0.f;

    // g-independent: plain-logit max, local chain + 16-lane butterfly
    float lm[4];
    #pragma unroll
    for (int r = 0; r < 4; ++r) {
        lm[r] = acc[0][r];
        #pragma unroll
        for (int j = 1; j < 10; ++j) lm[r] = fmaxf(lm[r], acc[j][r]);
    }
    #pragma unroll
    for (int d = 8; d >= 1; d >>= 1)
        #pragma unroll
        for (int r = 0; r < 4; ++r)
            lm[r] = fmaxf(lm[r], __shfl_xor(lm[r], d, 64));

    // g-dependent: argmax of logits+gumbel (col = cbase+16j ascending -> '>' keeps first idx)
    float zm[4]; int zi[4];
    #pragma unroll
    for (int r = 0; r < 4; ++r) {
        zm[r] = acc[0][r] + g[r][0]; zi[r] = cbase;
        #pragma unroll
        for (int j = 1; j < 10; ++j) {
            float zj = acc[j][r] + g[r][j];
            if (zj > zm[r]) { zm[r] = zj; zi[r] = cbase + 16 * j; }
        }
    }
    #pragma unroll
    for (int d = 8; d >= 1; d >>= 1) {
        #pragma unroll
        for (int r = 0; r < 4; ++r) {
            float oz = __shfl_xor(zm[r], d, 64); int oi = __shfl_xor(zi[r], d, 64);
            if (oz > zm[r] || (oz == zm[r] && oi < zi[r])) { zm[r] = oz; zi[r] = oi; }
        }
    }

    // exchange wave-level stats with group partner (wid^1)
    if (cn == 0) {
        #pragma unroll
        for (int r = 0; r < 4; ++r) {
            float4 e; e.x = zm[r]; e.y = __int_as_float(zi[r]); e.z = lm[r]; e.w = 0.f;
            ex[wid][4 * q + r] = e;
        }
    }
    __syncthreads();
    const int pw = wid ^ 1;
    #pragma unroll
    for (int r = 0; r < 4; ++r) {
        float4 e = ex[pw][4 * q + r];
        float pz = e.x; int pi = __float_as_int(e.y);
        if (pz > zm[r] || (pz == zm[r] && pi < zi[r])) { zm[r] = pz; zi[r] = pi; }
        lm[r] = fmaxf(lm[r], e.z);
    }

    // softmax numerators with group max; wave-level partial sums
    float pm[4][10], ps[4];
    #pragma unroll
    for (int r = 0; r < 4; ++r) {
        ps[r] = 0.f;
        #pragma unroll
        for (int j = 0; j < 10; ++j) {
            float p = __expf(acc[j][r] - lm[r]);
            pm[r][j] = p; ps[r] += p;
        }
    }
    #pragma unroll
    for (int d = 8; d >= 1; d >>= 1)
        #pragma unroll
        for (int r = 0; r < 4; ++r)
            ps[r] += __shfl_xor(ps[r], d, 64);

    if (cn == 0) {
        #pragma unroll
        for (int r = 0; r < 4; ++r) ex2[wid * 16 + 4 * q + r] = ps[r];
    }
    __syncthreads();
    float inv[4];
    #pragma unroll
    for (int r = 0; r < 4; ++r)
        inv[r] = mrow[r] / (ps[r] + ex2[pw * 16 + 4 * q + r]);

    // marginal column partials: sum over this wave's 16 rows, then across q (same cn)
    float part[10];
    #pragma unroll
    for (int j = 0; j < 10; ++j) {
        part[j] = pm[0][j] * inv[0] + pm[1][j] * inv[1] + pm[2][j] * inv[2] + pm[3][j] * inv[3];
        part[j] += __shfl_xor(part[j], 16, 64);
        part[j] += __shfl_xor(part[j], 32, 64);
    }
    if (q == 0) {
        #pragma unroll
        for (int j = 0; j < 10; ++j)
            mg[wm * GV + cbase + 16 * j] = part[j];   // wn slices disjoint; wm rows disjoint
    }
    // winning indices -> row table (one wave per group: wn==0 -> g0, wn==2 -> g1)
    if ((wn == 0 || wn == 2) && cn == 0) {
        int grp = wn >> 1;
        #pragma unroll
        for (int r = 0; r < 4; ++r)
            rowtab[wm * 16 + 4 * q + r][grp] = zi[r] - grp * V;
    }
    __syncthreads();

    // ---- marginal atomics, mask count, codevector gather ----
    for (int c = tid; c < GV; c += 512)
        atomicAdd(&ws[c], mg[c] + mg[GV + c]);
    if (wid == 0) {
        int mr = (tn < BM) ? (mask[row0 + tn] != 0) : 0;
        unsigned long long b = __ballot(mr);
        if (tn == 0) atomicAdd(&ws[GV], (float)__popcll(b));
    }
    {
        const int row = tid >> 4;          // 0..31
        const int six = tid & 15;
        #pragma unroll
        for (int i = 0; i < 4; ++i) {
            int e4  = six + 16 * i;        // 0..63 float4s of the 256-float out row
            int grp = e4 >> 5;
            int off = e4 & 31;
            int idx = rowtab[row][grp];
            float4 vv = ((const float4*)(codevec + ((size_t)grp * V + idx) * DG))[off];
            ((float4*)(out + (size_t)(row0 + row) * (2 * DG)))[e4] = vv;
        }
    }
}

__global__ void gumbel_vq_finalize(const float* __restrict__ ws, float* __restrict__ out)
{
    __shared__ float red[GV];
    int t = threadIdx.x;
    float cnt = ws[GV];
    float p = ws[t] / cnt;
    red[t] = p * logf(p + 1e-7f);
    __syncthreads();
    if (t == 0) {
        float e0 = 0.f, e1 = 0.f;
        for (int i = 0; i < V; ++i)  e0 += red[i];
        for (int i = V; i < GV; ++i) e1 += red[i];
        out[(size_t)N_ROWS * 2 * DG] = expf(-e0) + expf(-e1);
    }
}

extern "C" void kernel_launch(void* const* d_in, const int* in_sizes, int n_in,
                              void* d_out, int out_size, void* d_ws, size_t ws_size,
                              hipStream_t stream)
{
    const float* hidden  = (const float*)d_in[0];
    const int*   mask    = (const int*)  d_in[1];
    const float* gumbel  = (const float*)d_in[2];
    const float* W       = (const float*)d_in[3];
    const float* bias    = (const float*)d_in[4];
    const float* codevec = (const float*)d_in[5];
    float* out = (float*)d_out;
    float* ws  = (float*)d_ws;
    // ws layout: [0..639] marginal, [640] mask count, +4096B: W bf16 fragment pack (655 KB).
    // A bf16 fragment pack (33,554,432 B) lives in the OUT buffer (fits; barrier-ordered:
    // each block reads only its own rows' apack before its barriers, writes out after;
    // per-row byte ranges of apack and out coincide, so blocks never alias each other).
    short* wpack = (short*)((char*)d_ws + 4096);
    short* apack = (short*)d_out;

    hipMemsetAsync(d_ws, 0, (GV + 1) * sizeof(float), stream);
    pack_w<<<160, 256, 0, stream>>>(W, wpack);
    pack_a<<<8192, 256, 0, stream>>>(hidden, apack);
    gumbel_vq_main<<<N_ROWS / BM, 512, 0, stream>>>(apack, mask, gumbel, wpack, bias, codevec, out, ws);
    gumbel_vq_finalize<<<1, GV, 0, stream>>>(ws, out);
}